// Round 3
// baseline (564.005 us; speedup 1.0000x reference)
//
#include <hip/hip_runtime.h>
#include <math.h>

#define B_ 32
#define N_ 8192
#define G_ 128
#define S_ 32
#define ENC_ 384

typedef __attribute__((ext_vector_type(8))) short short8;
typedef __attribute__((ext_vector_type(4))) float f32x4;

__device__ __forceinline__ unsigned short f2bf(float x) {
  unsigned u = __float_as_uint(x);
  u = u + 0x7fffu + ((u >> 16) & 1u);  // RNE
  return (unsigned short)(u >> 16);
}

// ============================== FPS ==============================
__global__ __launch_bounds__(1024) void fps_kernel(const float* __restrict__ pc,
                                                   int* __restrict__ rep) {
  #pragma clang fp contract(off)
  extern __shared__ char smraw[];
  unsigned long long* redbuf = (unsigned long long*)smraw;    // 16 * 8 B
  int* s_last = (int*)(smraw + 128);
  float* sx = (float*)(smraw + 144);
  float* sy = sx + N_;
  float* sz = sy + N_;
  const int b = blockIdx.x;
  const float* p = pc + (size_t)b * N_ * 3;
  const int tid = threadIdx.x;
  for (int i = tid; i < N_; i += 1024) {
    sx[i] = p[i * 3 + 0];
    sy[i] = p[i * 3 + 1];
    sz[i] = p[i * 3 + 2];
  }
  __syncthreads();
  float X[8], Y[8], Z[8], D[8];
  #pragma unroll
  for (int j = 0; j < 8; ++j) {
    const int idx = tid + j * 1024;
    X[j] = sx[idx]; Y[j] = sy[idx]; Z[j] = sz[idx];
    D[j] = INFINITY;
  }
  int last = 0;
  const int lane = tid & 63, wave = tid >> 6;
  for (int k = 0; k < G_; ++k) {
    if (tid == 0) rep[b * G_ + k] = last;
    const float px = sx[last], py = sy[last], pz = sz[last];
    float bestv = -1.0f;
    int besti = 0;
    #pragma unroll
    for (int j = 0; j < 8; ++j) {
      const float dx = X[j] - px, dy = Y[j] - py, dz = Z[j] - pz;
      float dist = dx * dx;
      dist += dy * dy;
      dist += dz * dz;
      const float dj = fminf(D[j], dist);
      D[j] = dj;
      if (dj > bestv) { bestv = dj; besti = tid + j * 1024; }
    }
    unsigned long long key =
        ((unsigned long long)__float_as_uint(bestv) << 32) | (unsigned)(8191 - besti);
    #pragma unroll
    for (int off = 32; off >= 1; off >>= 1) {
      const unsigned long long o = __shfl_xor(key, off);
      if (o > key) key = o;
    }
    if (lane == 0) redbuf[wave] = key;
    __syncthreads();
    if (tid == 0) {
      unsigned long long kk = redbuf[0];
      #pragma unroll
      for (int w = 1; w < 16; ++w) {
        const unsigned long long o = redbuf[w];
        if (o > kk) kk = o;
      }
      *s_last = 8191 - (int)(kk & 0xFFFFFFFFu);
    }
    __syncthreads();
    last = *s_last;
  }
}

// ============================== KNN ==============================
// One block (256 thr) per (b,g). d2 = (nq+nt) - 2*dot, matching reference.
// 32 rounds of min-extraction with CACHED per-thread local min: only the
// winning thread rescans its 32 candidates. Double-buffered cross-wave LDS
// -> one barrier per round. Keys u64 (sortable-dist | index) are unique, so
// tie-breaking (smaller index) is identical to lax.top_k.
__global__ __launch_bounds__(256) void knn_kernel(const float* __restrict__ pc,
                                                  const int* __restrict__ rep,
                                                  int* __restrict__ nn) {
  #pragma clang fp contract(off)
  const int bg = blockIdx.x;
  const int b = bg >> 7;
  const float* p = pc + (size_t)b * N_ * 3;
  const int tid = threadIdx.x;
  const int ridx = rep[bg];
  const float qx = p[ridx * 3 + 0], qy = p[ridx * 3 + 1], qz = p[ridx * 3 + 2];
  float nq = qx * qx;
  nq += qy * qy;
  nq += qz * qz;
  unsigned ub[32];
  #pragma unroll
  for (int j = 0; j < 32; ++j) {
    const int idx = tid + j * 256;
    const float tx = p[idx * 3 + 0], ty = p[idx * 3 + 1], tz = p[idx * 3 + 2];
    float nt = tx * tx;
    nt += ty * ty;
    nt += tz * tz;
    float dt = qx * tx;
    dt += qy * ty;
    dt += qz * tz;
    const float d2 = (nq + nt) - 2.0f * dt;
    unsigned u = __float_as_uint(d2);
    u = (u & 0x80000000u) ? ~u : (u | 0x80000000u);  // float -> sortable uint
    ub[j] = u;
  }
  // cached per-thread local min
  unsigned long long loc = ~0ull;
  #pragma unroll
  for (int j = 0; j < 32; ++j) {
    const unsigned long long kj =
        ((unsigned long long)ub[j] << 32) | (unsigned)(tid + j * 256);
    loc = kj < loc ? kj : loc;
  }
  __shared__ unsigned long long redbuf[2][4];
  const int lane = tid & 63, wave = tid >> 6;
  for (int r = 0; r < S_; ++r) {
    unsigned long long key = loc;
    #pragma unroll
    for (int off = 32; off >= 1; off >>= 1) {
      const unsigned long long o = __shfl_xor(key, off);
      key = o < key ? o : key;
    }
    const int cur = r & 1;
    if (lane == 0) redbuf[cur][wave] = key;
    __syncthreads();
    unsigned long long kk = redbuf[cur][0];
    #pragma unroll
    for (int w = 1; w < 4; ++w) {
      const unsigned long long o = redbuf[cur][w];
      kk = o < kk ? o : kk;
    }
    const int widx = (int)(kk & 0xFFFFFFFFu);
    if (tid == 0) nn[bg * S_ + r] = widx;
    if ((widx & 255) == tid) {
      // kill candidate and recompute local min (killed key = max sortable)
      const int wj = widx >> 8;
      unsigned long long nl = ~0ull;
      #pragma unroll
      for (int j = 0; j < 32; ++j) {
        if (j == wj) ub[j] = 0xFFFFFFFFu;
        const unsigned long long kj =
            ((unsigned long long)ub[j] << 32) | (unsigned)(tid + j * 256);
        nl = kj < nl ? kj : nl;
      }
      loc = nl;
    }
  }
}

// ==================== LAPACK-faithful 3x3 eigh ====================
__device__ __forceinline__ double slapy2d(double x, double y) {
  return sqrt(x * x + y * y);
}

__device__ void slartg_(double f, double g, double& c, double& s, double& r) {
  if (g == 0.0) { c = 1.0; s = 0.0; r = f; }
  else if (f == 0.0) { c = 0.0; s = copysign(1.0, g); r = fabs(g); }
  else {
    const double d = sqrt(f * f + g * g);
    c = fabs(f) / d;
    r = copysign(d, f);
    s = g / r;
  }
}

__device__ void slaev2_(double a, double b, double c, double& rt1, double& rt2,
                        double& cs1, double& sn1) {
  const double sm = a + c, df = a - c;
  const double adf = fabs(df), tb = b + b, ab = fabs(tb);
  double acmx, acmn;
  if (fabs(a) > fabs(c)) { acmx = a; acmn = c; } else { acmx = c; acmn = a; }
  double rt;
  if (adf > ab) rt = adf * sqrt(1.0 + (ab / adf) * (ab / adf));
  else if (adf < ab) rt = ab * sqrt(1.0 + (adf / ab) * (adf / ab));
  else rt = ab * sqrt(2.0);
  int sgn1;
  if (sm < 0.0) { rt1 = 0.5 * (sm - rt); sgn1 = -1; rt2 = (acmx / rt1) * acmn - (b / rt1) * b; }
  else if (sm > 0.0) { rt1 = 0.5 * (sm + rt); sgn1 = 1; rt2 = (acmx / rt1) * acmn - (b / rt1) * b; }
  else { rt1 = 0.5 * rt; rt2 = -0.5 * rt; sgn1 = 1; }
  double cs;
  int sgn2;
  if (df >= 0.0) { cs = df + rt; sgn2 = 1; } else { cs = df - rt; sgn2 = -1; }
  const double acs = fabs(cs);
  if (acs > ab) {
    const double ct = -tb / cs;
    sn1 = 1.0 / sqrt(1.0 + ct * ct);
    cs1 = ct * sn1;
  } else {
    if (ab == 0.0) { cs1 = 1.0; sn1 = 0.0; }
    else {
      const double tn = -cs / tb;
      cs1 = 1.0 / sqrt(1.0 + tn * tn);
      sn1 = tn * cs1;
    }
  }
  if (sgn1 == sgn2) { const double tn = cs1; cs1 = -sn1; sn1 = tn; }
}

__device__ void eigh33_lapack(const double A[3][3], double dout[3], double Zo[3][3]) {
  double d[3], e[2];
  double Z[3][3];
  {
    const double a00 = A[0][0], a10 = A[1][0], a20 = A[2][0];
    const double a11 = A[1][1], a21 = A[2][1], a22 = A[2][2];
    if (fabs(a20) == 0.0) {
      d[0] = a00; d[1] = a11; d[2] = a22; e[0] = a10; e[1] = a21;
      Z[0][0] = 1; Z[0][1] = 0; Z[0][2] = 0;
      Z[1][0] = 0; Z[1][1] = 1; Z[1][2] = 0;
      Z[2][0] = 0; Z[2][1] = 0; Z[2][2] = 1;
    } else {
      const double beta = -copysign(slapy2d(a10, a20), a10);
      const double tau = (beta - a10) / beta;
      const double v2 = a20 / (a10 - beta);
      const double h11 = 1.0 - tau;
      const double h12 = -tau * v2;
      const double h22 = 1.0 - tau * v2 * v2;
      const double m10 = h11 * a10 + h12 * a20;
      const double m11 = h11 * a11 + h12 * a21;
      const double m12 = h11 * a21 + h12 * a22;
      const double m21 = h12 * a11 + h22 * a21;
      const double m22 = h12 * a21 + h22 * a22;
      d[0] = a00;
      d[1] = m11 * h11 + m12 * h12;
      d[2] = m21 * h12 + m22 * h22;
      e[0] = m10;
      e[1] = m21 * h11 + m22 * h12;
      Z[0][0] = 1; Z[0][1] = 0;   Z[0][2] = 0;
      Z[1][0] = 0; Z[1][1] = h11; Z[1][2] = h12;
      Z[2][0] = 0; Z[2][1] = h12; Z[2][2] = h22;
    }
  }
  const double eps = 5.9604644775390625e-08;
  const double eps2 = eps * eps;
  const double safmin = 1.1754943508222875e-38;
  int jtot = 0;
  const int nmaxit = 90;
  int l1 = 0;
  while (l1 <= 2) {
    if (l1 > 0) e[l1 - 1] = 0.0;
    int m;
    for (m = l1; m <= 1; ++m) {
      const double tst = fabs(e[m]);
      if (tst == 0.0) break;
      if (tst <= (sqrt(fabs(d[m])) * sqrt(fabs(d[m + 1]))) * eps) { e[m] = 0.0; break; }
    }
    int l = l1;
    const int lsv = l;
    int lend = m;
    const int lendsv = lend;
    l1 = m + 1;
    if (lend == l) continue;
    if (fabs(d[lend]) < fabs(d[l])) { lend = lsv; l = lendsv; }
    if (lend > l) {
      for (;;) {
        int mq;
        for (mq = l; mq <= lend - 1; ++mq) {
          const double tst = e[mq] * e[mq];
          if (tst <= (eps2 * fabs(d[mq])) * fabs(d[mq + 1]) + safmin) break;
        }
        if (mq < lend) e[mq] = 0.0;
        double p = d[l];
        if (mq == l) { d[l] = p; l = l + 1; if (l <= lend) continue; break; }
        if (mq == l + 1) {
          double rt1, rt2, c, s;
          slaev2_(d[l], e[l], d[l + 1], rt1, rt2, c, s);
          for (int i = 0; i < 3; ++i) {
            const double t1 = Z[i][l + 1], t0 = Z[i][l];
            Z[i][l + 1] = c * t1 - s * t0;
            Z[i][l] = s * t1 + c * t0;
          }
          d[l] = rt1; d[l + 1] = rt2; e[l] = 0.0;
          l += 2;
          if (l <= lend) continue;
          break;
        }
        if (jtot == nmaxit) break;
        ++jtot;
        double g = (d[l + 1] - p) / (2.0 * e[l]);
        double r = slapy2d(g, 1.0);
        g = d[mq] - p + e[l] / (g + copysign(r, g));
        double s = 1.0, c = 1.0;
        p = 0.0;
        double csv[2], ssv[2];
        for (int i = mq - 1; i >= l; --i) {
          const double f = s * e[i];
          const double bb = c * e[i];
          slartg_(g, f, c, s, r);
          if (i != mq - 1) e[i + 1] = r;
          g = d[i + 1] - p;
          r = (d[i] - g) * s + 2.0 * c * bb;
          p = s * r;
          d[i + 1] = g + p;
          g = c * r - bb;
          csv[i] = c; ssv[i] = -s;
        }
        const int mm = mq - l + 1;
        for (int j = mm - 2; j >= 0; --j) {
          const double ct = csv[l + j], st = ssv[l + j];
          for (int i = 0; i < 3; ++i) {
            const double t1 = Z[i][l + j + 1];
            Z[i][l + j + 1] = ct * t1 - st * Z[i][l + j];
            Z[i][l + j] = st * t1 + ct * Z[i][l + j];
          }
        }
        d[l] = d[l] - p;
        e[l] = g;
      }
    } else {
      for (;;) {
        int mq;
        for (mq = l; mq >= lend + 1; --mq) {
          const double tst = e[mq - 1] * e[mq - 1];
          if (tst <= (eps2 * fabs(d[mq])) * fabs(d[mq - 1]) + safmin) break;
        }
        if (mq > lend) e[mq - 1] = 0.0;
        double p = d[l];
        if (mq == l) { d[l] = p; l = l - 1; if (l >= lend) continue; break; }
        if (mq == l - 1) {
          double rt1, rt2, c, s;
          slaev2_(d[l - 1], e[l - 1], d[l], rt1, rt2, c, s);
          for (int i = 0; i < 3; ++i) {
            const double t1 = Z[i][l], t0 = Z[i][l - 1];
            Z[i][l] = c * t1 - s * t0;
            Z[i][l - 1] = s * t1 + c * t0;
          }
          d[l - 1] = rt1; d[l] = rt2; e[l - 1] = 0.0;
          l -= 2;
          if (l >= lend) continue;
          break;
        }
        if (jtot == nmaxit) break;
        ++jtot;
        double g = (d[l - 1] - p) / (2.0 * e[l - 1]);
        double r = slapy2d(g, 1.0);
        g = d[mq] - p + e[l - 1] / (g + copysign(r, g));
        double s = 1.0, c = 1.0;
        p = 0.0;
        double csv[2], ssv[2];
        for (int i = mq; i <= l - 1; ++i) {
          const double f = s * e[i];
          const double bb = c * e[i];
          slartg_(g, f, c, s, r);
          if (i != mq) e[i - 1] = r;
          g = d[i] - p;
          r = (d[i + 1] - g) * s + 2.0 * c * bb;
          p = s * r;
          d[i] = g + p;
          g = c * r - bb;
          csv[i] = c; ssv[i] = s;
        }
        const int mm = l - mq + 1;
        for (int j = 0; j <= mm - 2; ++j) {
          const double ct = csv[mq + j], st = ssv[mq + j];
          for (int i = 0; i < 3; ++i) {
            const double t1 = Z[i][mq + j + 1];
            Z[i][mq + j + 1] = ct * t1 - st * Z[i][mq + j];
            Z[i][mq + j] = st * t1 + ct * Z[i][mq + j];
          }
        }
        d[l] = d[l] - p;
        e[l - 1] = g;
      }
    }
  }
  for (int ii = 1; ii < 3; ++ii) {
    const int i = ii - 1;
    int k = i;
    double p = d[i];
    for (int j = ii; j < 3; ++j)
      if (d[j] < p) { k = j; p = d[j]; }
    if (k != i) {
      d[k] = d[i];
      d[i] = p;
      for (int q = 0; q < 3; ++q) {
        const double t = Z[q][i];
        Z[q][i] = Z[q][k];
        Z[q][k] = t;
      }
    }
  }
  dout[0] = d[0]; dout[1] = d[1]; dout[2] = d[2];
  for (int i = 0; i < 3; ++i)
    for (int j = 0; j < 3; ++j) Zo[i][j] = Z[i][j];
}

// ============================== LRF ==============================
__global__ __launch_bounds__(64) void lrf_kernel(const float* __restrict__ pc,
                                                 const int* __restrict__ rep,
                                                 const int* __restrict__ nn,
                                                 float* __restrict__ rot) {
  #pragma clang fp contract(off)
  const int bg = blockIdx.x;
  const int b = bg >> 7;
  const float* p = pc + (size_t)b * N_ * 3;
  const int lane = threadIdx.x;
  const int s = lane & 31;
  const int ridx = rep[bg];
  const float cx = p[ridx * 3 + 0], cy = p[ridx * 3 + 1], cz = p[ridx * 3 + 2];
  const int idx = nn[bg * S_ + s];
  const float nx = p[idx * 3 + 0] - cx;
  const float ny = p[idx * 3 + 1] - cy;
  const float nz = p[idx * 3 + 2] - cz;
  float nrm2 = nx * nx;
  nrm2 += ny * ny;
  nrm2 += nz * nz;
  const float nrm = sqrtf(nrm2);
  float wmax = nrm;
  #pragma unroll
  for (int off = 16; off >= 1; off >>= 1) wmax = fmaxf(wmax, __shfl_xor(wmax, off));
  float w = wmax - nrm;
  float wsum = w;
  #pragma unroll
  for (int off = 16; off >= 1; off >>= 1) wsum += __shfl_xor(wsum, off);
  w = w / (wsum + 1e-6f);
  const float spx = 100.0f * nx, spy = 100.0f * ny, spz = 100.0f * nz;
  const float wx = w * spx, wy = w * spy, wz = w * spz;
  float c00 = wx * spx, c01 = wx * spy, c02 = wx * spz;
  float c11 = wy * spy, c12 = wy * spz, c22 = wz * spz;
  #pragma unroll
  for (int off = 16; off >= 1; off >>= 1) {
    c00 += __shfl_xor(c00, off); c01 += __shfl_xor(c01, off); c02 += __shfl_xor(c02, off);
    c11 += __shfl_xor(c11, off); c12 += __shfl_xor(c12, off); c22 += __shfl_xor(c22, off);
  }
  double A[3][3] = {{(double)c00, (double)c01, (double)c02},
                    {(double)c01, (double)c11, (double)c12},
                    {(double)c02, (double)c12, (double)c22}};
  double lam[3], Zm[3][3];
  eigh33_lapack(A, lam, Zm);
  float zx = (float)Zm[0][0], zy = (float)Zm[1][0], zz = (float)Zm[2][0];
  float xx = (float)Zm[0][2], xy = (float)Zm[1][2], xz = (float)Zm[2][2];
  float pj = zx * nx;
  pj += zy * ny;
  pj += zz * nz;
  int npos = __popcll(__ballot(pj > 0.0f) & 0xFFFFFFFFull);
  if (npos < 16) { zx = -zx; zy = -zy; zz = -zz; }
  pj = xx * nx;
  pj += xy * ny;
  pj += xz * nz;
  npos = __popcll(__ballot(pj > 0.0f) & 0xFFFFFFFFull);
  if (npos < 16) { xx = -xx; xy = -xy; xz = -xz; }
  const float yx = zy * xz - zz * xy;
  const float yy = zz * xx - zx * xz;
  const float yz = zx * xy - zy * xx;
  if (lane < 32) {
    float r0 = nx * zx; r0 += ny * zy; r0 += nz * zz;
    float r1 = nx * yx; r1 += ny * yy; r1 += nz * yz;
    float r2 = nx * xx; r2 += ny * xy; r2 += nz * xz;
    const size_t base = (size_t)(bg * S_ + s) * 3;
    rot[base + 0] = r0;
    rot[base + 1] = r1;
    rot[base + 2] = r2;
  }
}

// ==================== weight pre-tiling (f32 -> bf16, MFMA-tiled) ====================
#define P2_ 4096    // 16*4*64
#define P3_ 16384   // 32*8*64
#define P4_ 24576   // 24*16*64
__global__ __launch_bounds__(256) void convw_kernel(
    const float* __restrict__ W2, const float* __restrict__ W3,
    const float* __restrict__ W4, short* __restrict__ w2t,
    short* __restrict__ w3gt, short* __restrict__ w3ft,
    short* __restrict__ w4t) {
  int t = blockIdx.x * 256 + threadIdx.x;
  const float* src;
  short* dst;
  if (t < P2_) {
    const int lane = t & 63, kt = (t >> 6) & 3, nt = t >> 8;
    src = W2 + (nt * 16 + (lane & 15)) * 128 + kt * 32 + ((lane >> 4) << 3);
    dst = w2t + t * 8;
  } else if (t < P2_ + P3_) {
    const int p = t - P2_;
    const int lane = p & 63, kt = (p >> 6) & 7, nt = p >> 9;
    src = W3 + (nt * 16 + (lane & 15)) * 512 + kt * 32 + ((lane >> 4) << 3);
    dst = w3gt + p * 8;
  } else if (t < P2_ + 2 * P3_) {
    const int p = t - P2_ - P3_;
    const int lane = p & 63, kt = (p >> 6) & 7, nt = p >> 9;
    src = W3 + (nt * 16 + (lane & 15)) * 512 + 256 + kt * 32 + ((lane >> 4) << 3);
    dst = w3ft + p * 8;
  } else if (t < P2_ + 2 * P3_ + P4_) {
    const int p = t - P2_ - 2 * P3_;
    const int lane = p & 63, kt = (p >> 6) & 15, nt = p >> 10;
    src = W4 + (nt * 16 + (lane & 15)) * 512 + kt * 32 + ((lane >> 4) << 3);
    dst = w4t + p * 8;
  } else {
    return;
  }
  short8 v;
  #pragma unroll
  for (int j = 0; j < 8; ++j) v[j] = (short)f2bf(src[j]);
  *(short8*)dst = v;
}

// ============================== fused MFMA MLP ==============================
#define OFF_A3   0        // f2   [64][256] bf16  (32768 B)
#define OFF_R1   32768    // f1 [64][128] then f3 [64][512] bf16 (65536 B)
#define OFF_FGA  98304    // fg A-tile [16][256] bf16 (8192 B)
#define OFF_BASE 106496   // base [2][512] f32 (4096 B)
#define OFF_SROT 110592   // rot [64][3] f32 (768 B)
#define LDS_MLP  111360

__device__ __forceinline__ int swz(int row, int byteoff) {
  return byteoff ^ ((row & 7) << 4);
}

__global__ __launch_bounds__(512) void mlp_kernel(
    const float* __restrict__ rot,
    const float* __restrict__ W1, const float* __restrict__ b1,
    const float* __restrict__ g1, const float* __restrict__ be1,
    const float* __restrict__ b2, const float* __restrict__ b3,
    const float* __restrict__ g2, const float* __restrict__ be2,
    const float* __restrict__ b4,
    const short* __restrict__ w2t, const short* __restrict__ w3gt,
    const short* __restrict__ w3ft, const short* __restrict__ w4t,
    float* __restrict__ out) {
  extern __shared__ char sm[];
  const int tid = threadIdx.x;
  const int lane = tid & 63, wave = tid >> 6;
  const int l15 = lane & 15, lq = lane >> 4;  // col-in-tile, lane quarter
  const int bg0 = blockIdx.x * 2;
  const float inv_s = 1.0f / sqrtf(1.0f + 1e-5f);

  // ---- phase 0: stage rot, zero fgA ----
  if (tid < 192) ((float*)(sm + OFF_SROT))[tid] = rot[(size_t)bg0 * 96 + tid];
  for (int i = tid; i < 2048; i += 512) ((int*)(sm + OFF_FGA))[i] = 0;
  __syncthreads();

  // ---- L1: rot[64x3] * W1^T -> relu(bn) -> A2 [64][128] bf16 ----
  {
    const int o = tid & 127;
    const int rbase = tid >> 7;  // 0..3
    const float w10 = W1[o * 3], w11 = W1[o * 3 + 1], w12 = W1[o * 3 + 2];
    const float b1v = b1[o], sc = g1[o] * inv_s, sh = be1[o];
    const float* sr = (const float*)(sm + OFF_SROT);
    #pragma unroll
    for (int t = 0; t < 16; ++t) {
      const int row = rbase + t * 4;
      float v = sr[row * 3] * w10 + sr[row * 3 + 1] * w11 + sr[row * 3 + 2] * w12 + b1v;
      v = fmaxf(v * sc + sh, 0.0f);
      *(unsigned short*)(sm + OFF_R1 + swz(row, row * 256 + o * 2)) = f2bf(v);
    }
  }
  __syncthreads();

  // ---- L2: f2[64][256] = A2[64x128] x W2^T (+b2); fg = colmax per group ----
  {
    f32x4 acc[2][4];
    #pragma unroll
    for (int j = 0; j < 2; ++j)
      #pragma unroll
      for (int mt = 0; mt < 4; ++mt) acc[j][mt] = (f32x4){0.f, 0.f, 0.f, 0.f};
    for (int kt = 0; kt < 4; ++kt) {
      short8 af[4];
      #pragma unroll
      for (int mt = 0; mt < 4; ++mt) {
        const int row = mt * 16 + l15;
        af[mt] = *(const short8*)(sm + OFF_R1 + swz(row, row * 256 + kt * 64 + (lq << 4)));
      }
      #pragma unroll
      for (int j = 0; j < 2; ++j) {
        const int nt = wave * 2 + j;
        const short8 bf = *(const short8*)(w2t + ((nt * 4 + kt) * 64 + lane) * 8);
        #pragma unroll
        for (int mt = 0; mt < 4; ++mt)
          acc[j][mt] = __builtin_amdgcn_mfma_f32_16x16x32_bf16(af[mt], bf, acc[j][mt], 0, 0, 0);
      }
    }
    #pragma unroll
    for (int j = 0; j < 2; ++j) {
      const int n = (wave * 2 + j) * 16 + l15;
      const float b2v = b2[n];
      float pm0 = -INFINITY, pm1 = -INFINITY;
      #pragma unroll
      for (int mt = 0; mt < 4; ++mt) {
        #pragma unroll
        for (int reg = 0; reg < 4; ++reg) {
          const int r = mt * 16 + (lq << 2) + reg;
          const float v = acc[j][mt][reg] + b2v;
          *(unsigned short*)(sm + OFF_A3 + swz(r, r * 512 + n * 2)) = f2bf(v);
          if (mt < 2) pm0 = fmaxf(pm0, v); else pm1 = fmaxf(pm1, v);
        }
      }
      pm0 = fmaxf(pm0, __shfl_xor(pm0, 16)); pm0 = fmaxf(pm0, __shfl_xor(pm0, 32));
      pm1 = fmaxf(pm1, __shfl_xor(pm1, 16)); pm1 = fmaxf(pm1, __shfl_xor(pm1, 32));
      if (lane < 16)
        *(unsigned short*)(sm + OFF_FGA + swz(0, n * 2)) = f2bf(pm0);
      else if (lane < 32)
        *(unsigned short*)(sm + OFF_FGA + swz(1, 512 + n * 2)) = f2bf(pm1);
    }
  }
  __syncthreads();

  // ---- FG: base[2][512] = fgA[16x256] x W3[:, :256]^T (+b3), rows 0,1 ----
  {
    f32x4 ac[4];
    #pragma unroll
    for (int q = 0; q < 4; ++q) ac[q] = (f32x4){0.f, 0.f, 0.f, 0.f};
    for (int kt = 0; kt < 8; ++kt) {
      const int row = l15;
      const short8 af = *(const short8*)(sm + OFF_FGA + swz(row, row * 512 + kt * 64 + (lq << 4)));
      #pragma unroll
      for (int q = 0; q < 4; ++q) {
        const short8 bf = *(const short8*)(w3gt + (((wave * 4 + q) * 8 + kt) * 64 + lane) * 8);
        ac[q] = __builtin_amdgcn_mfma_f32_16x16x32_bf16(af, bf, ac[q], 0, 0, 0);
      }
    }
    if (lq == 0) {
      #pragma unroll
      for (int q = 0; q < 4; ++q) {
        const int n = (wave * 4 + q) * 16 + l15;
        const float b3v = b3[n];
        ((float*)(sm + OFF_BASE))[n] = ac[q][0] + b3v;        // group 0 (row 0)
        ((float*)(sm + OFF_BASE))[512 + n] = ac[q][1] + b3v;  // group 1 (row 1)
      }
    }
  }
  __syncthreads();

  // ---- L3: f3[64][512] = relu(bn(base + A3[64x256] x W3[:, 256:]^T)) ----
  {
    f32x4 ac[4][4];
    #pragma unroll
    for (int mt = 0; mt < 4; ++mt)
      #pragma unroll
      for (int q = 0; q < 4; ++q) ac[mt][q] = (f32x4){0.f, 0.f, 0.f, 0.f};
    for (int kt = 0; kt < 8; ++kt) {
      short8 af[4];
      #pragma unroll
      for (int mt = 0; mt < 4; ++mt) {
        const int row = mt * 16 + l15;
        af[mt] = *(const short8*)(sm + OFF_A3 + swz(row, row * 512 + kt * 64 + (lq << 4)));
      }
      #pragma unroll
      for (int q = 0; q < 4; ++q) {
        const short8 bf = *(const short8*)(w3ft + (((wave * 4 + q) * 8 + kt) * 64 + lane) * 8);
        #pragma unroll
        for (int mt = 0; mt < 4; ++mt)
          ac[mt][q] = __builtin_amdgcn_mfma_f32_16x16x32_bf16(af[mt], bf, ac[mt][q], 0, 0, 0);
      }
    }
    #pragma unroll
    for (int q = 0; q < 4; ++q) {
      const int n = (wave * 4 + q) * 16 + l15;
      const float sc = g2[n] * inv_s, sh = be2[n];
      const float bs0 = ((float*)(sm + OFF_BASE))[n];
      const float bs1 = ((float*)(sm + OFF_BASE))[512 + n];
      #pragma unroll
      for (int mt = 0; mt < 4; ++mt) {
        const float bsv = (mt < 2) ? bs0 : bs1;
        #pragma unroll
        for (int reg = 0; reg < 4; ++reg) {
          const int r = mt * 16 + (lq << 2) + reg;
          const float v = fmaxf((ac[mt][q][reg] + bsv) * sc + sh, 0.0f);
          *(unsigned short*)(sm + OFF_R1 + swz(r, r * 1024 + n * 2)) = f2bf(v);
        }
      }
    }
  }
  __syncthreads();

  // ---- L4: out[2][384] = colmax_s(f3[64x512] x W4^T) + b4 ----
  {
    f32x4 ac[4][3];
    #pragma unroll
    for (int mt = 0; mt < 4; ++mt)
      #pragma unroll
      for (int q = 0; q < 3; ++q) ac[mt][q] = (f32x4){0.f, 0.f, 0.f, 0.f};
    for (int kt = 0; kt < 16; ++kt) {
      short8 af[4];
      #pragma unroll
      for (int mt = 0; mt < 4; ++mt) {
        const int row = mt * 16 + l15;
        af[mt] = *(const short8*)(sm + OFF_R1 + swz(row, row * 1024 + kt * 64 + (lq << 4)));
      }
      #pragma unroll
      for (int q = 0; q < 3; ++q) {
        const short8 bf = *(const short8*)(w4t + (((wave * 3 + q) * 16 + kt) * 64 + lane) * 8);
        #pragma unroll
        for (int mt = 0; mt < 4; ++mt)
          ac[mt][q] = __builtin_amdgcn_mfma_f32_16x16x32_bf16(af[mt], bf, ac[mt][q], 0, 0, 0);
      }
    }
    #pragma unroll
    for (int q = 0; q < 3; ++q) {
      const int n = (wave * 3 + q) * 16 + l15;
      float m0 = -INFINITY, m1 = -INFINITY;
      #pragma unroll
      for (int reg = 0; reg < 4; ++reg) {
        m0 = fmaxf(m0, fmaxf(ac[0][q][reg], ac[1][q][reg]));
        m1 = fmaxf(m1, fmaxf(ac[2][q][reg], ac[3][q][reg]));
      }
      m0 = fmaxf(m0, __shfl_xor(m0, 16)); m0 = fmaxf(m0, __shfl_xor(m0, 32));
      m1 = fmaxf(m1, __shfl_xor(m1, 16)); m1 = fmaxf(m1, __shfl_xor(m1, 32));
      const float b4v = b4[n];
      if (lane < 16) out[(size_t)bg0 * ENC_ + n] = m0 + b4v;
      else if (lane < 32) out[(size_t)(bg0 + 1) * ENC_ + n] = m1 + b4v;
    }
  }
}

// ============================== launch ==============================
extern "C" void kernel_launch(void* const* d_in, const int* in_sizes, int n_in,
                              void* d_out, int out_size, void* d_ws, size_t ws_size,
                              hipStream_t stream) {
  const float* pc  = (const float*)d_in[0];
  const float* W1  = (const float*)d_in[1];
  const float* b1  = (const float*)d_in[2];
  const float* g1  = (const float*)d_in[3];
  const float* be1 = (const float*)d_in[4];
  const float* W2  = (const float*)d_in[5];
  const float* b2  = (const float*)d_in[6];
  const float* W3  = (const float*)d_in[7];
  const float* b3  = (const float*)d_in[8];
  const float* g2  = (const float*)d_in[9];
  const float* be2 = (const float*)d_in[10];
  const float* W4  = (const float*)d_in[11];
  const float* b4  = (const float*)d_in[12];
  float* out = (float*)d_out;
  char* ws = (char*)d_ws;
  int* rep    = (int*)ws;                         // 16384 B
  int* nn     = (int*)(ws + 16384);               // 524288 B
  float* rot  = (float*)(ws + 540672);            // 1572864 B
  short* w2t  = (short*)(ws + 2113536);           // 65536 B
  short* w3gt = (short*)(ws + 2179072);           // 262144 B
  short* w3ft = (short*)(ws + 2441216);           // 262144 B
  short* w4t  = (short*)(ws + 2703360);           // 393216 B (ends 3096576)

  const size_t fps_lds = 144 + (size_t)3 * N_ * 4;  // 98448 B

  convw_kernel<<<240, 256, 0, stream>>>(W2, W3, W4, w2t, w3gt, w3ft, w4t);
  fps_kernel<<<B_, 1024, fps_lds, stream>>>(pc, rep);
  knn_kernel<<<B_ * G_, 256, 0, stream>>>(pc, rep, nn);
  lrf_kernel<<<B_ * G_, 64, 0, stream>>>(pc, rep, nn, rot);
  mlp_kernel<<<B_ * G_ / 2, 512, LDS_MLP, stream>>>(
      rot, W1, b1, g1, be1, b2, b3, g2, be2, b4, w2t, w3gt, w3ft, w4t, out);
}

// Round 4
// 485.234 us; speedup vs baseline: 1.1623x; 1.1623x over previous
//
#include <hip/hip_runtime.h>
#include <math.h>

#define B_ 32
#define N_ 8192
#define G_ 128
#define S_ 32
#define ENC_ 384

typedef __attribute__((ext_vector_type(8))) short short8;
typedef __attribute__((ext_vector_type(4))) float f32x4;

__device__ __forceinline__ unsigned short f2bf(float x) {
  unsigned u = __float_as_uint(x);
  u = u + 0x7fffu + ((u >> 16) & 1u);  // RNE
  return (unsigned short)(u >> 16);
}

// DPP xor-involution max step for u64 keys (all lanes valid: full permutations)
template <int CTRL>
__device__ __forceinline__ unsigned long long dpp_xor_max(unsigned long long k) {
  const int lo = (int)(unsigned)k, hi = (int)(unsigned)(k >> 32);
  const int olo = __builtin_amdgcn_update_dpp(0, lo, CTRL, 0xF, 0xF, true);
  const int ohi = __builtin_amdgcn_update_dpp(0, hi, CTRL, 0xF, 0xF, true);
  const unsigned long long o =
      ((unsigned long long)(unsigned)ohi << 32) | (unsigned)(unsigned)olo;
  return o > k ? o : k;
}

// ============================== FPS ==============================
// One block per batch. Per-round: per-thread argmax (regs) -> wave reduce via
// DPP involutions (xor1,2,7,15) + shfl_xor(16,32) -> lane0 writes LDS ->
// ONE barrier -> all threads redundantly reduce 16 wave-keys. Double-buffered
// redbuf removes the second barrier. Semantics identical to jnp reference.
__global__ __launch_bounds__(1024) void fps_kernel(const float* __restrict__ pc,
                                                   int* __restrict__ rep) {
  #pragma clang fp contract(off)
  extern __shared__ char smraw[];
  unsigned long long (*redbuf)[16] = (unsigned long long (*)[16])smraw;  // 2*16*8 B
  float* sx = (float*)(smraw + 256);
  float* sy = sx + N_;
  float* sz = sy + N_;
  const int b = blockIdx.x;
  const float* p = pc + (size_t)b * N_ * 3;
  const int tid = threadIdx.x;
  for (int i = tid; i < N_; i += 1024) {
    sx[i] = p[i * 3 + 0];
    sy[i] = p[i * 3 + 1];
    sz[i] = p[i * 3 + 2];
  }
  __syncthreads();
  float X[8], Y[8], Z[8], D[8];
  #pragma unroll
  for (int j = 0; j < 8; ++j) {
    const int idx = tid + j * 1024;
    X[j] = sx[idx]; Y[j] = sy[idx]; Z[j] = sz[idx];
    D[j] = INFINITY;
  }
  int last = 0;
  const int lane = tid & 63, wave = tid >> 6;
  for (int k = 0; k < G_; ++k) {
    if (tid == 0) rep[b * G_ + k] = last;
    const float px = sx[last], py = sy[last], pz = sz[last];
    float bestv = -1.0f;
    int besti = 0;
    #pragma unroll
    for (int j = 0; j < 8; ++j) {
      const float dx = X[j] - px, dy = Y[j] - py, dz = Z[j] - pz;
      float dist = dx * dx;
      dist += dy * dy;
      dist += dz * dz;
      const float dj = fminf(D[j], dist);
      D[j] = dj;
      if (dj > bestv) { bestv = dj; besti = tid + j * 1024; }  // ascending idx scan
    }
    // maximize (value, 8191-idx): tie -> smallest index
    unsigned long long key =
        ((unsigned long long)__float_as_uint(bestv) << 32) | (unsigned)(8191 - besti);
    key = dpp_xor_max<0xB1>(key);   // quad_perm(1,0,3,2) = xor1
    key = dpp_xor_max<0x4E>(key);   // quad_perm(2,3,0,1) = xor2
    key = dpp_xor_max<0x141>(key);  // row_half_mirror = xor7
    key = dpp_xor_max<0x140>(key);  // row_mirror = xor15
    { const unsigned long long o = __shfl_xor(key, 16); if (o > key) key = o; }
    { const unsigned long long o = __shfl_xor(key, 32); if (o > key) key = o; }
    const int par = k & 1;
    if (lane == 0) redbuf[par][wave] = key;
    __syncthreads();
    unsigned long long kk = redbuf[par][0];
    #pragma unroll
    for (int w = 1; w < 16; ++w) {
      const unsigned long long o = redbuf[par][w];
      if (o > kk) kk = o;
    }
    last = 8191 - (int)(kk & 0xFFFFFFFFu);
  }
}

// ============================== KNN ==============================
// One block (256 thr) per (b,g). Exact top-32 selection via radix/histogram
// select over unique 45-bit keys (sortable_d2<<13 | idx): <=6 passes of
// 256-bin histogram + scan to find the exact cutoff prefix (terminates via
// need==bincount), then collect exactly 32 keys and rank-sort. Selection
// and ordering bit-identical to lax.top_k (ascending d2, ties by index).
__global__ __launch_bounds__(256) void knn_kernel(const float* __restrict__ pc,
                                                  const int* __restrict__ rep,
                                                  int* __restrict__ nn) {
  #pragma clang fp contract(off)
  const int bg = blockIdx.x;
  const int b = bg >> 7;
  const float* p = pc + (size_t)b * N_ * 3;
  const int tid = threadIdx.x;
  const int lane = tid & 63, wave = tid >> 6;
  const int ridx = rep[bg];
  const float qx = p[ridx * 3 + 0], qy = p[ridx * 3 + 1], qz = p[ridx * 3 + 2];
  float nq = qx * qx;
  nq += qy * qy;
  nq += qz * qz;
  unsigned ub[32];
  #pragma unroll
  for (int j = 0; j < 32; ++j) {
    const int idx = tid + j * 256;
    const float tx = p[idx * 3 + 0], ty = p[idx * 3 + 1], tz = p[idx * 3 + 2];
    float nt = tx * tx;
    nt += ty * ty;
    nt += tz * tz;
    float dt = qx * tx;
    dt += qy * ty;
    dt += qz * tz;
    const float d2 = (nq + nt) - 2.0f * dt;
    unsigned u = __float_as_uint(d2);
    u = (u & 0x80000000u) ? ~u : (u | 0x80000000u);  // float -> sortable uint
    ub[j] = u;
  }

  __shared__ unsigned hist[256];
  __shared__ unsigned wsum[4];
  __shared__ int s_bin, s_cexc, s_hbin, s_cnt;
  __shared__ unsigned long long keys[32];

  unsigned long long curPrefix = 0;
  int need = 32;
  int prevShift = 45;
  int stopShift = 0;
  unsigned long long stopPrefix = 0;
  const int shifts[6] = {37, 29, 21, 13, 5, 0};
  #pragma unroll 1
  for (int pass = 0; pass < 6; ++pass) {
    const int sh = shifts[pass];
    const int width = prevShift - sh;
    const unsigned msk = (1u << width) - 1u;
    hist[tid] = 0;
    if (pass == 0 && tid == 0) s_cnt = 0;
    __syncthreads();
    #pragma unroll
    for (int j = 0; j < 32; ++j) {
      const unsigned long long key =
          ((unsigned long long)ub[j] << 13) | (unsigned)(tid + j * 256);
      if ((key >> prevShift) == curPrefix)
        atomicAdd(&hist[(unsigned)(key >> sh) & msk], 1u);
    }
    __syncthreads();
    const unsigned v = hist[tid];
    unsigned c = v;
    #pragma unroll
    for (int off = 1; off <= 32; off <<= 1) {
      const unsigned o = __shfl_up(c, (unsigned)off);
      if (lane >= off) c += o;
    }
    if (lane == 63) wsum[wave] = c;
    __syncthreads();
    unsigned pre = 0;
    if (wave > 0) pre += wsum[0];
    if (wave > 1) pre += wsum[1];
    if (wave > 2) pre += wsum[2];
    const unsigned cine = c + pre;
    const unsigned cexc = cine - v;
    if (cexc < (unsigned)need && (unsigned)need <= cine) {
      s_bin = tid;
      s_cexc = (int)cexc;
      s_hbin = (int)v;
    }
    __syncthreads();
    curPrefix = (curPrefix << width) | (unsigned)s_bin;
    need -= s_cexc;
    prevShift = sh;
    if (need == s_hbin) {  // take whole bin: exact 32-set determined
      stopShift = sh;
      stopPrefix = curPrefix;
      break;
    }
  }
  // collect exactly 32 keys with (key >> stopShift) <= stopPrefix
  #pragma unroll
  for (int j = 0; j < 32; ++j) {
    const unsigned long long key =
        ((unsigned long long)ub[j] << 13) | (unsigned)(tid + j * 256);
    if ((key >> stopShift) <= stopPrefix) {
      const int pos = atomicAdd(&s_cnt, 1);
      keys[pos] = key;
    }
  }
  __syncthreads();
  if (tid < 32) {
    const unsigned long long kt = keys[tid];
    int rank = 0;
    #pragma unroll
    for (int j = 0; j < 32; ++j) rank += (keys[j] < kt) ? 1 : 0;
    nn[bg * S_ + rank] = (int)(kt & 8191u);
  }
}

// ==================== LAPACK-faithful 3x3 eigh ====================
__device__ __forceinline__ double slapy2d(double x, double y) {
  return sqrt(x * x + y * y);
}

__device__ void slartg_(double f, double g, double& c, double& s, double& r) {
  if (g == 0.0) { c = 1.0; s = 0.0; r = f; }
  else if (f == 0.0) { c = 0.0; s = copysign(1.0, g); r = fabs(g); }
  else {
    const double d = sqrt(f * f + g * g);
    c = fabs(f) / d;
    r = copysign(d, f);
    s = g / r;
  }
}

__device__ void slaev2_(double a, double b, double c, double& rt1, double& rt2,
                        double& cs1, double& sn1) {
  const double sm = a + c, df = a - c;
  const double adf = fabs(df), tb = b + b, ab = fabs(tb);
  double acmx, acmn;
  if (fabs(a) > fabs(c)) { acmx = a; acmn = c; } else { acmx = c; acmn = a; }
  double rt;
  if (adf > ab) rt = adf * sqrt(1.0 + (ab / adf) * (ab / adf));
  else if (adf < ab) rt = ab * sqrt(1.0 + (adf / ab) * (adf / ab));
  else rt = ab * sqrt(2.0);
  int sgn1;
  if (sm < 0.0) { rt1 = 0.5 * (sm - rt); sgn1 = -1; rt2 = (acmx / rt1) * acmn - (b / rt1) * b; }
  else if (sm > 0.0) { rt1 = 0.5 * (sm + rt); sgn1 = 1; rt2 = (acmx / rt1) * acmn - (b / rt1) * b; }
  else { rt1 = 0.5 * rt; rt2 = -0.5 * rt; sgn1 = 1; }
  double cs;
  int sgn2;
  if (df >= 0.0) { cs = df + rt; sgn2 = 1; } else { cs = df - rt; sgn2 = -1; }
  const double acs = fabs(cs);
  if (acs > ab) {
    const double ct = -tb / cs;
    sn1 = 1.0 / sqrt(1.0 + ct * ct);
    cs1 = ct * sn1;
  } else {
    if (ab == 0.0) { cs1 = 1.0; sn1 = 0.0; }
    else {
      const double tn = -cs / tb;
      cs1 = 1.0 / sqrt(1.0 + tn * tn);
      sn1 = tn * cs1;
    }
  }
  if (sgn1 == sgn2) { const double tn = cs1; cs1 = -sn1; sn1 = tn; }
}

__device__ void eigh33_lapack(const double A[3][3], double dout[3], double Zo[3][3]) {
  double d[3], e[2];
  double Z[3][3];
  {
    const double a00 = A[0][0], a10 = A[1][0], a20 = A[2][0];
    const double a11 = A[1][1], a21 = A[2][1], a22 = A[2][2];
    if (fabs(a20) == 0.0) {
      d[0] = a00; d[1] = a11; d[2] = a22; e[0] = a10; e[1] = a21;
      Z[0][0] = 1; Z[0][1] = 0; Z[0][2] = 0;
      Z[1][0] = 0; Z[1][1] = 1; Z[1][2] = 0;
      Z[2][0] = 0; Z[2][1] = 0; Z[2][2] = 1;
    } else {
      const double beta = -copysign(slapy2d(a10, a20), a10);
      const double tau = (beta - a10) / beta;
      const double v2 = a20 / (a10 - beta);
      const double h11 = 1.0 - tau;
      const double h12 = -tau * v2;
      const double h22 = 1.0 - tau * v2 * v2;
      const double m10 = h11 * a10 + h12 * a20;
      const double m11 = h11 * a11 + h12 * a21;
      const double m12 = h11 * a21 + h12 * a22;
      const double m21 = h12 * a11 + h22 * a21;
      const double m22 = h12 * a21 + h22 * a22;
      d[0] = a00;
      d[1] = m11 * h11 + m12 * h12;
      d[2] = m21 * h12 + m22 * h22;
      e[0] = m10;
      e[1] = m21 * h11 + m22 * h12;
      Z[0][0] = 1; Z[0][1] = 0;   Z[0][2] = 0;
      Z[1][0] = 0; Z[1][1] = h11; Z[1][2] = h12;
      Z[2][0] = 0; Z[2][1] = h12; Z[2][2] = h22;
    }
  }
  const double eps = 5.9604644775390625e-08;
  const double eps2 = eps * eps;
  const double safmin = 1.1754943508222875e-38;
  int jtot = 0;
  const int nmaxit = 90;
  int l1 = 0;
  while (l1 <= 2) {
    if (l1 > 0) e[l1 - 1] = 0.0;
    int m;
    for (m = l1; m <= 1; ++m) {
      const double tst = fabs(e[m]);
      if (tst == 0.0) break;
      if (tst <= (sqrt(fabs(d[m])) * sqrt(fabs(d[m + 1]))) * eps) { e[m] = 0.0; break; }
    }
    int l = l1;
    const int lsv = l;
    int lend = m;
    const int lendsv = lend;
    l1 = m + 1;
    if (lend == l) continue;
    if (fabs(d[lend]) < fabs(d[l])) { lend = lsv; l = lendsv; }
    if (lend > l) {
      for (;;) {
        int mq;
        for (mq = l; mq <= lend - 1; ++mq) {
          const double tst = e[mq] * e[mq];
          if (tst <= (eps2 * fabs(d[mq])) * fabs(d[mq + 1]) + safmin) break;
        }
        if (mq < lend) e[mq] = 0.0;
        double p = d[l];
        if (mq == l) { d[l] = p; l = l + 1; if (l <= lend) continue; break; }
        if (mq == l + 1) {
          double rt1, rt2, c, s;
          slaev2_(d[l], e[l], d[l + 1], rt1, rt2, c, s);
          for (int i = 0; i < 3; ++i) {
            const double t1 = Z[i][l + 1], t0 = Z[i][l];
            Z[i][l + 1] = c * t1 - s * t0;
            Z[i][l] = s * t1 + c * t0;
          }
          d[l] = rt1; d[l + 1] = rt2; e[l] = 0.0;
          l += 2;
          if (l <= lend) continue;
          break;
        }
        if (jtot == nmaxit) break;
        ++jtot;
        double g = (d[l + 1] - p) / (2.0 * e[l]);
        double r = slapy2d(g, 1.0);
        g = d[mq] - p + e[l] / (g + copysign(r, g));
        double s = 1.0, c = 1.0;
        p = 0.0;
        double csv[2], ssv[2];
        for (int i = mq - 1; i >= l; --i) {
          const double f = s * e[i];
          const double bb = c * e[i];
          slartg_(g, f, c, s, r);
          if (i != mq - 1) e[i + 1] = r;
          g = d[i + 1] - p;
          r = (d[i] - g) * s + 2.0 * c * bb;
          p = s * r;
          d[i + 1] = g + p;
          g = c * r - bb;
          csv[i] = c; ssv[i] = -s;
        }
        const int mm = mq - l + 1;
        for (int j = mm - 2; j >= 0; --j) {
          const double ct = csv[l + j], st = ssv[l + j];
          for (int i = 0; i < 3; ++i) {
            const double t1 = Z[i][l + j + 1];
            Z[i][l + j + 1] = ct * t1 - st * Z[i][l + j];
            Z[i][l + j] = st * t1 + ct * Z[i][l + j];
          }
        }
        d[l] = d[l] - p;
        e[l] = g;
      }
    } else {
      for (;;) {
        int mq;
        for (mq = l; mq >= lend + 1; --mq) {
          const double tst = e[mq - 1] * e[mq - 1];
          if (tst <= (eps2 * fabs(d[mq])) * fabs(d[mq - 1]) + safmin) break;
        }
        if (mq > lend) e[mq - 1] = 0.0;
        double p = d[l];
        if (mq == l) { d[l] = p; l = l - 1; if (l >= lend) continue; break; }
        if (mq == l - 1) {
          double rt1, rt2, c, s;
          slaev2_(d[l - 1], e[l - 1], d[l], rt1, rt2, c, s);
          for (int i = 0; i < 3; ++i) {
            const double t1 = Z[i][l], t0 = Z[i][l - 1];
            Z[i][l] = c * t1 - s * t0;
            Z[i][l - 1] = s * t1 + c * t0;
          }
          d[l - 1] = rt1; d[l] = rt2; e[l - 1] = 0.0;
          l -= 2;
          if (l >= lend) continue;
          break;
        }
        if (jtot == nmaxit) break;
        ++jtot;
        double g = (d[l - 1] - p) / (2.0 * e[l - 1]);
        double r = slapy2d(g, 1.0);
        g = d[mq] - p + e[l - 1] / (g + copysign(r, g));
        double s = 1.0, c = 1.0;
        p = 0.0;
        double csv[2], ssv[2];
        for (int i = mq; i <= l - 1; ++i) {
          const double f = s * e[i];
          const double bb = c * e[i];
          slartg_(g, f, c, s, r);
          if (i != mq) e[i - 1] = r;
          g = d[i] - p;
          r = (d[i + 1] - g) * s + 2.0 * c * bb;
          p = s * r;
          d[i] = g + p;
          g = c * r - bb;
          csv[i] = c; ssv[i] = s;
        }
        const int mm = l - mq + 1;
        for (int j = 0; j <= mm - 2; ++j) {
          const double ct = csv[mq + j], st = ssv[mq + j];
          for (int i = 0; i < 3; ++i) {
            const double t1 = Z[i][mq + j + 1];
            Z[i][mq + j + 1] = ct * t1 - st * Z[i][mq + j];
            Z[i][mq + j] = st * t1 + ct * Z[i][mq + j];
          }
        }
        d[l] = d[l] - p;
        e[l - 1] = g;
      }
    }
  }
  for (int ii = 1; ii < 3; ++ii) {
    const int i = ii - 1;
    int k = i;
    double p = d[i];
    for (int j = ii; j < 3; ++j)
      if (d[j] < p) { k = j; p = d[j]; }
    if (k != i) {
      d[k] = d[i];
      d[i] = p;
      for (int q = 0; q < 3; ++q) {
        const double t = Z[q][i];
        Z[q][i] = Z[q][k];
        Z[q][k] = t;
      }
    }
  }
  dout[0] = d[0]; dout[1] = d[1]; dout[2] = d[2];
  for (int i = 0; i < 3; ++i)
    for (int j = 0; j < 3; ++j) Zo[i][j] = Z[i][j];
}

// ============================== LRF ==============================
__global__ __launch_bounds__(64) void lrf_kernel(const float* __restrict__ pc,
                                                 const int* __restrict__ rep,
                                                 const int* __restrict__ nn,
                                                 float* __restrict__ rot) {
  #pragma clang fp contract(off)
  const int bg = blockIdx.x;
  const int b = bg >> 7;
  const float* p = pc + (size_t)b * N_ * 3;
  const int lane = threadIdx.x;
  const int s = lane & 31;
  const int ridx = rep[bg];
  const float cx = p[ridx * 3 + 0], cy = p[ridx * 3 + 1], cz = p[ridx * 3 + 2];
  const int idx = nn[bg * S_ + s];
  const float nx = p[idx * 3 + 0] - cx;
  const float ny = p[idx * 3 + 1] - cy;
  const float nz = p[idx * 3 + 2] - cz;
  float nrm2 = nx * nx;
  nrm2 += ny * ny;
  nrm2 += nz * nz;
  const float nrm = sqrtf(nrm2);
  float wmax = nrm;
  #pragma unroll
  for (int off = 16; off >= 1; off >>= 1) wmax = fmaxf(wmax, __shfl_xor(wmax, off));
  float w = wmax - nrm;
  float wsum = w;
  #pragma unroll
  for (int off = 16; off >= 1; off >>= 1) wsum += __shfl_xor(wsum, off);
  w = w / (wsum + 1e-6f);
  const float spx = 100.0f * nx, spy = 100.0f * ny, spz = 100.0f * nz;
  const float wx = w * spx, wy = w * spy, wz = w * spz;
  float c00 = wx * spx, c01 = wx * spy, c02 = wx * spz;
  float c11 = wy * spy, c12 = wy * spz, c22 = wz * spz;
  #pragma unroll
  for (int off = 16; off >= 1; off >>= 1) {
    c00 += __shfl_xor(c00, off); c01 += __shfl_xor(c01, off); c02 += __shfl_xor(c02, off);
    c11 += __shfl_xor(c11, off); c12 += __shfl_xor(c12, off); c22 += __shfl_xor(c22, off);
  }
  double A[3][3] = {{(double)c00, (double)c01, (double)c02},
                    {(double)c01, (double)c11, (double)c12},
                    {(double)c02, (double)c12, (double)c22}};
  double lam[3], Zm[3][3];
  eigh33_lapack(A, lam, Zm);
  float zx = (float)Zm[0][0], zy = (float)Zm[1][0], zz = (float)Zm[2][0];
  float xx = (float)Zm[0][2], xy = (float)Zm[1][2], xz = (float)Zm[2][2];
  float pj = zx * nx;
  pj += zy * ny;
  pj += zz * nz;
  int npos = __popcll(__ballot(pj > 0.0f) & 0xFFFFFFFFull);
  if (npos < 16) { zx = -zx; zy = -zy; zz = -zz; }
  pj = xx * nx;
  pj += xy * ny;
  pj += xz * nz;
  npos = __popcll(__ballot(pj > 0.0f) & 0xFFFFFFFFull);
  if (npos < 16) { xx = -xx; xy = -xy; xz = -xz; }
  const float yx = zy * xz - zz * xy;
  const float yy = zz * xx - zx * xz;
  const float yz = zx * xy - zy * xx;
  if (lane < 32) {
    float r0 = nx * zx; r0 += ny * zy; r0 += nz * zz;
    float r1 = nx * yx; r1 += ny * yy; r1 += nz * yz;
    float r2 = nx * xx; r2 += ny * xy; r2 += nz * xz;
    const size_t base = (size_t)(bg * S_ + s) * 3;
    rot[base + 0] = r0;
    rot[base + 1] = r1;
    rot[base + 2] = r2;
  }
}

// ==================== weight pre-tiling (f32 -> bf16, MFMA-tiled) ====================
#define P2_ 4096    // 16*4*64
#define P3_ 16384   // 32*8*64
#define P4_ 24576   // 24*16*64
__global__ __launch_bounds__(256) void convw_kernel(
    const float* __restrict__ W2, const float* __restrict__ W3,
    const float* __restrict__ W4, short* __restrict__ w2t,
    short* __restrict__ w3gt, short* __restrict__ w3ft,
    short* __restrict__ w4t) {
  int t = blockIdx.x * 256 + threadIdx.x;
  const float* src;
  short* dst;
  if (t < P2_) {
    const int lane = t & 63, kt = (t >> 6) & 3, nt = t >> 8;
    src = W2 + (nt * 16 + (lane & 15)) * 128 + kt * 32 + ((lane >> 4) << 3);
    dst = w2t + t * 8;
  } else if (t < P2_ + P3_) {
    const int p = t - P2_;
    const int lane = p & 63, kt = (p >> 6) & 7, nt = p >> 9;
    src = W3 + (nt * 16 + (lane & 15)) * 512 + kt * 32 + ((lane >> 4) << 3);
    dst = w3gt + p * 8;
  } else if (t < P2_ + 2 * P3_) {
    const int p = t - P2_ - P3_;
    const int lane = p & 63, kt = (p >> 6) & 7, nt = p >> 9;
    src = W3 + (nt * 16 + (lane & 15)) * 512 + 256 + kt * 32 + ((lane >> 4) << 3);
    dst = w3ft + p * 8;
  } else if (t < P2_ + 2 * P3_ + P4_) {
    const int p = t - P2_ - 2 * P3_;
    const int lane = p & 63, kt = (p >> 6) & 15, nt = p >> 10;
    src = W4 + (nt * 16 + (lane & 15)) * 512 + kt * 32 + ((lane >> 4) << 3);
    dst = w4t + p * 8;
  } else {
    return;
  }
  short8 v;
  #pragma unroll
  for (int j = 0; j < 8; ++j) v[j] = (short)f2bf(src[j]);
  *(short8*)dst = v;
}

// ============================== fused MFMA MLP ==============================
#define OFF_A3   0        // f2   [64][256] bf16  (32768 B)
#define OFF_R1   32768    // f1 [64][128] then f3 [64][512] bf16 (65536 B)
#define OFF_FGA  98304    // fg A-tile [16][256] bf16 (8192 B)
#define OFF_BASE 106496   // base [2][512] f32 (4096 B)
#define OFF_SROT 110592   // rot [64][3] f32 (768 B)
#define LDS_MLP  111360

__device__ __forceinline__ int swz(int row, int byteoff) {
  return byteoff ^ ((row & 7) << 4);
}

__global__ __launch_bounds__(512) void mlp_kernel(
    const float* __restrict__ rot,
    const float* __restrict__ W1, const float* __restrict__ b1,
    const float* __restrict__ g1, const float* __restrict__ be1,
    const float* __restrict__ b2, const float* __restrict__ b3,
    const float* __restrict__ g2, const float* __restrict__ be2,
    const float* __restrict__ b4,
    const short* __restrict__ w2t, const short* __restrict__ w3gt,
    const short* __restrict__ w3ft, const short* __restrict__ w4t,
    float* __restrict__ out) {
  extern __shared__ char sm[];
  const int tid = threadIdx.x;
  const int lane = tid & 63, wave = tid >> 6;
  const int l15 = lane & 15, lq = lane >> 4;  // col-in-tile, lane quarter
  const int bg0 = blockIdx.x * 2;
  const float inv_s = 1.0f / sqrtf(1.0f + 1e-5f);

  // ---- phase 0: stage rot, zero fgA ----
  if (tid < 192) ((float*)(sm + OFF_SROT))[tid] = rot[(size_t)bg0 * 96 + tid];
  for (int i = tid; i < 2048; i += 512) ((int*)(sm + OFF_FGA))[i] = 0;
  __syncthreads();

  // ---- L1: rot[64x3] * W1^T -> relu(bn) -> A2 [64][128] bf16 ----
  {
    const int o = tid & 127;
    const int rbase = tid >> 7;  // 0..3
    const float w10 = W1[o * 3], w11 = W1[o * 3 + 1], w12 = W1[o * 3 + 2];
    const float b1v = b1[o], sc = g1[o] * inv_s, sh = be1[o];
    const float* sr = (const float*)(sm + OFF_SROT);
    #pragma unroll
    for (int t = 0; t < 16; ++t) {
      const int row = rbase + t * 4;
      float v = sr[row * 3] * w10 + sr[row * 3 + 1] * w11 + sr[row * 3 + 2] * w12 + b1v;
      v = fmaxf(v * sc + sh, 0.0f);
      *(unsigned short*)(sm + OFF_R1 + swz(row, row * 256 + o * 2)) = f2bf(v);
    }
  }
  __syncthreads();

  // ---- L2: f2[64][256] = A2[64x128] x W2^T (+b2); fg = colmax per group ----
  {
    f32x4 acc[2][4];
    #pragma unroll
    for (int j = 0; j < 2; ++j)
      #pragma unroll
      for (int mt = 0; mt < 4; ++mt) acc[j][mt] = (f32x4){0.f, 0.f, 0.f, 0.f};
    for (int kt = 0; kt < 4; ++kt) {
      short8 af[4];
      #pragma unroll
      for (int mt = 0; mt < 4; ++mt) {
        const int row = mt * 16 + l15;
        af[mt] = *(const short8*)(sm + OFF_R1 + swz(row, row * 256 + kt * 64 + (lq << 4)));
      }
      #pragma unroll
      for (int j = 0; j < 2; ++j) {
        const int nt = wave * 2 + j;
        const short8 bf = *(const short8*)(w2t + ((nt * 4 + kt) * 64 + lane) * 8);
        #pragma unroll
        for (int mt = 0; mt < 4; ++mt)
          acc[j][mt] = __builtin_amdgcn_mfma_f32_16x16x32_bf16(af[mt], bf, acc[j][mt], 0, 0, 0);
      }
    }
    #pragma unroll
    for (int j = 0; j < 2; ++j) {
      const int n = (wave * 2 + j) * 16 + l15;
      const float b2v = b2[n];
      float pm0 = -INFINITY, pm1 = -INFINITY;
      #pragma unroll
      for (int mt = 0; mt < 4; ++mt) {
        #pragma unroll
        for (int reg = 0; reg < 4; ++reg) {
          const int r = mt * 16 + (lq << 2) + reg;
          const float v = acc[j][mt][reg] + b2v;
          *(unsigned short*)(sm + OFF_A3 + swz(r, r * 512 + n * 2)) = f2bf(v);
          if (mt < 2) pm0 = fmaxf(pm0, v); else pm1 = fmaxf(pm1, v);
        }
      }
      pm0 = fmaxf(pm0, __shfl_xor(pm0, 16)); pm0 = fmaxf(pm0, __shfl_xor(pm0, 32));
      pm1 = fmaxf(pm1, __shfl_xor(pm1, 16)); pm1 = fmaxf(pm1, __shfl_xor(pm1, 32));
      if (lane < 16)
        *(unsigned short*)(sm + OFF_FGA + swz(0, n * 2)) = f2bf(pm0);
      else if (lane < 32)
        *(unsigned short*)(sm + OFF_FGA + swz(1, 512 + n * 2)) = f2bf(pm1);
    }
  }
  __syncthreads();

  // ---- FG: base[2][512] = fgA[16x256] x W3[:, :256]^T (+b3), rows 0,1 ----
  {
    f32x4 ac[4];
    #pragma unroll
    for (int q = 0; q < 4; ++q) ac[q] = (f32x4){0.f, 0.f, 0.f, 0.f};
    for (int kt = 0; kt < 8; ++kt) {
      const int row = l15;
      const short8 af = *(const short8*)(sm + OFF_FGA + swz(row, row * 512 + kt * 64 + (lq << 4)));
      #pragma unroll
      for (int q = 0; q < 4; ++q) {
        const short8 bf = *(const short8*)(w3gt + (((wave * 4 + q) * 8 + kt) * 64 + lane) * 8);
        ac[q] = __builtin_amdgcn_mfma_f32_16x16x32_bf16(af, bf, ac[q], 0, 0, 0);
      }
    }
    if (lq == 0) {
      #pragma unroll
      for (int q = 0; q < 4; ++q) {
        const int n = (wave * 4 + q) * 16 + l15;
        const float b3v = b3[n];
        ((float*)(sm + OFF_BASE))[n] = ac[q][0] + b3v;        // group 0 (row 0)
        ((float*)(sm + OFF_BASE))[512 + n] = ac[q][1] + b3v;  // group 1 (row 1)
      }
    }
  }
  __syncthreads();

  // ---- L3: f3[64][512] = relu(bn(base + A3[64x256] x W3[:, 256:]^T)) ----
  {
    f32x4 ac[4][4];
    #pragma unroll
    for (int mt = 0; mt < 4; ++mt)
      #pragma unroll
      for (int q = 0; q < 4; ++q) ac[mt][q] = (f32x4){0.f, 0.f, 0.f, 0.f};
    for (int kt = 0; kt < 8; ++kt) {
      short8 af[4];
      #pragma unroll
      for (int mt = 0; mt < 4; ++mt) {
        const int row = mt * 16 + l15;
        af[mt] = *(const short8*)(sm + OFF_A3 + swz(row, row * 512 + kt * 64 + (lq << 4)));
      }
      #pragma unroll
      for (int q = 0; q < 4; ++q) {
        const short8 bf = *(const short8*)(w3ft + (((wave * 4 + q) * 8 + kt) * 64 + lane) * 8);
        #pragma unroll
        for (int mt = 0; mt < 4; ++mt)
          ac[mt][q] = __builtin_amdgcn_mfma_f32_16x16x32_bf16(af[mt], bf, ac[mt][q], 0, 0, 0);
      }
    }
    #pragma unroll
    for (int q = 0; q < 4; ++q) {
      const int n = (wave * 4 + q) * 16 + l15;
      const float sc = g2[n] * inv_s, sh = be2[n];
      const float bs0 = ((float*)(sm + OFF_BASE))[n];
      const float bs1 = ((float*)(sm + OFF_BASE))[512 + n];
      #pragma unroll
      for (int mt = 0; mt < 4; ++mt) {
        const float bsv = (mt < 2) ? bs0 : bs1;
        #pragma unroll
        for (int reg = 0; reg < 4; ++reg) {
          const int r = mt * 16 + (lq << 2) + reg;
          const float v = fmaxf((ac[mt][q][reg] + bsv) * sc + sh, 0.0f);
          *(unsigned short*)(sm + OFF_R1 + swz(r, r * 1024 + n * 2)) = f2bf(v);
        }
      }
    }
  }
  __syncthreads();

  // ---- L4: out[2][384] = colmax_s(f3[64x512] x W4^T) + b4 ----
  {
    f32x4 ac[4][3];
    #pragma unroll
    for (int mt = 0; mt < 4; ++mt)
      #pragma unroll
      for (int q = 0; q < 3; ++q) ac[mt][q] = (f32x4){0.f, 0.f, 0.f, 0.f};
    for (int kt = 0; kt < 16; ++kt) {
      short8 af[4];
      #pragma unroll
      for (int mt = 0; mt < 4; ++mt) {
        const int row = mt * 16 + l15;
        af[mt] = *(const short8*)(sm + OFF_R1 + swz(row, row * 1024 + kt * 64 + (lq << 4)));
      }
      #pragma unroll
      for (int q = 0; q < 3; ++q) {
        const short8 bf = *(const short8*)(w4t + (((wave * 3 + q) * 16 + kt) * 64 + lane) * 8);
        #pragma unroll
        for (int mt = 0; mt < 4; ++mt)
          ac[mt][q] = __builtin_amdgcn_mfma_f32_16x16x32_bf16(af[mt], bf, ac[mt][q], 0, 0, 0);
      }
    }
    #pragma unroll
    for (int q = 0; q < 3; ++q) {
      const int n = (wave * 3 + q) * 16 + l15;
      float m0 = -INFINITY, m1 = -INFINITY;
      #pragma unroll
      for (int reg = 0; reg < 4; ++reg) {
        m0 = fmaxf(m0, fmaxf(ac[0][q][reg], ac[1][q][reg]));
        m1 = fmaxf(m1, fmaxf(ac[2][q][reg], ac[3][q][reg]));
      }
      m0 = fmaxf(m0, __shfl_xor(m0, 16)); m0 = fmaxf(m0, __shfl_xor(m0, 32));
      m1 = fmaxf(m1, __shfl_xor(m1, 16)); m1 = fmaxf(m1, __shfl_xor(m1, 32));
      const float b4v = b4[n];
      if (lane < 16) out[(size_t)bg0 * ENC_ + n] = m0 + b4v;
      else if (lane < 32) out[(size_t)(bg0 + 1) * ENC_ + n] = m1 + b4v;
    }
  }
}

// ============================== launch ==============================
extern "C" void kernel_launch(void* const* d_in, const int* in_sizes, int n_in,
                              void* d_out, int out_size, void* d_ws, size_t ws_size,
                              hipStream_t stream) {
  const float* pc  = (const float*)d_in[0];
  const float* W1  = (const float*)d_in[1];
  const float* b1  = (const float*)d_in[2];
  const float* g1  = (const float*)d_in[3];
  const float* be1 = (const float*)d_in[4];
  const float* W2  = (const float*)d_in[5];
  const float* b2  = (const float*)d_in[6];
  const float* W3  = (const float*)d_in[7];
  const float* b3  = (const float*)d_in[8];
  const float* g2  = (const float*)d_in[9];
  const float* be2 = (const float*)d_in[10];
  const float* W4  = (const float*)d_in[11];
  const float* b4  = (const float*)d_in[12];
  float* out = (float*)d_out;
  char* ws = (char*)d_ws;
  int* rep    = (int*)ws;                         // 16384 B
  int* nn     = (int*)(ws + 16384);               // 524288 B
  float* rot  = (float*)(ws + 540672);            // 1572864 B
  short* w2t  = (short*)(ws + 2113536);           // 65536 B
  short* w3gt = (short*)(ws + 2179072);           // 262144 B
  short* w3ft = (short*)(ws + 2441216);           // 262144 B
  short* w4t  = (short*)(ws + 2703360);           // 393216 B (ends 3096576)

  const size_t fps_lds = 256 + (size_t)3 * N_ * 4;  // 98560 B

  convw_kernel<<<240, 256, 0, stream>>>(W2, W3, W4, w2t, w3gt, w3ft, w4t);
  fps_kernel<<<B_, 1024, fps_lds, stream>>>(pc, rep);
  knn_kernel<<<B_ * G_, 256, 0, stream>>>(pc, rep, nn);
  lrf_kernel<<<B_ * G_, 64, 0, stream>>>(pc, rep, nn, rot);
  mlp_kernel<<<B_ * G_ / 2, 512, LDS_MLP, stream>>>(
      rot, W1, b1, g1, be1, b2, b3, g2, be2, b4, w2t, w3gt, w3ft, w4t, out);
}